// Round 1
// baseline (900.036 us; speedup 1.0000x reference)
//
#include <hip/hip_runtime.h>

// Problem constants (fixed by the reference):
//   N=51200 nodes, E=800000 edges, G=128 graphs, DIN=DE=DOUT=64, DG=128
// Math restructuring:
//   msg = relu(relu(A[src] + B[dst] + h_edge@W1c + b1) @ W2 + b2)
//   gg[g] = sum over edges with graph(dst)=g of msg        [G,64]
//   sum_node[g] = gg[g] @ Wn + cnt_g * bn                  [G,64]
//   out[g] = relu(concat(u[g], sum_node[g]) @ Wg + bg)     [G,128]

#define WB() __builtin_amdgcn_wave_barrier()

// ---------------------------------------------------------------------------
// K0: AB[i][0:64] = h_node[i] @ W1[0:64,:],  AB[i][64:128] = h_node[i] @ W1[64:128,:]
// wave-per-node; W columns in VGPRs (lane j holds column j), x broadcast via LDS b128
__global__ __launch_bounds__(256) void k_node_ab(
    const float* __restrict__ h_node, const float* __restrict__ W1,
    float* __restrict__ AB, int N)
{
    __shared__ float sx[4][64];
    const int wave = threadIdx.x >> 6, lane = threadIdx.x & 63;
    float wa[64], wb[64];
#pragma unroll
    for (int k = 0; k < 64; ++k) {
        wa[k] = W1[k * 64 + lane];          // W1a[k][lane]
        wb[k] = W1[(64 + k) * 64 + lane];   // W1b[k][lane]
    }
    const int gw = blockIdx.x * 4 + wave, nw = gridDim.x * 4;
    for (int i = gw; i < N; i += nw) {
        sx[wave][lane] = h_node[i * 64 + lane];
        WB();
        float a = 0.f, b = 0.f;
#pragma unroll
        for (int k4 = 0; k4 < 16; ++k4) {
            float4 xv = *(const float4*)&sx[wave][k4 * 4];   // wave-uniform addr -> broadcast
            a = fmaf(xv.x, wa[4 * k4 + 0], a); b = fmaf(xv.x, wb[4 * k4 + 0], b);
            a = fmaf(xv.y, wa[4 * k4 + 1], a); b = fmaf(xv.y, wb[4 * k4 + 1], b);
            a = fmaf(xv.z, wa[4 * k4 + 2], a); b = fmaf(xv.z, wb[4 * k4 + 2], b);
            a = fmaf(xv.w, wa[4 * k4 + 3], a); b = fmaf(xv.w, wb[4 * k4 + 3], b);
        }
        WB();
        AB[i * 128 + lane] = a;
        AB[i * 128 + 64 + lane] = b;
    }
}

// ---------------------------------------------------------------------------
// K_cnt: nodes per graph
__global__ __launch_bounds__(256) void k_count(
    const int* __restrict__ gid, int* __restrict__ cnt, int N)
{
    int i = blockIdx.x * blockDim.x + threadIdx.x;
    if (i < N) atomicAdd(&cnt[gid[i]], 1);
}

// ---------------------------------------------------------------------------
// K1: fused edge MLP + per-graph scatter accumulate
// wave-per-edge; W1c/W2 columns in VGPRs; per-graph partials in LDS
__global__ __launch_bounds__(256) void k_edge(
    const float* __restrict__ h_edge, const float* __restrict__ AB,
    const float* __restrict__ W1, const float* __restrict__ b1,
    const float* __restrict__ W2, const float* __restrict__ b2,
    const int* __restrict__ src, const int* __restrict__ dst,
    const int* __restrict__ node_graph_id,
    float* __restrict__ gg, int E)
{
    __shared__ float sgg[128 * 64];   // per-graph partial sums, 32 KB
    __shared__ float sx[4][64];       // layer-1 input broadcast tile
    __shared__ float st[4][64];       // layer-2 input broadcast tile
    const int wave = threadIdx.x >> 6, lane = threadIdx.x & 63;

    for (int i = threadIdx.x; i < 128 * 64; i += 256) sgg[i] = 0.f;

    float w1c[64], w2[64];
#pragma unroll
    for (int k = 0; k < 64; ++k) {
        w1c[k] = W1[(128 + k) * 64 + lane];  // W1c[k][lane]
        w2[k]  = W2[k * 64 + lane];          // W2[k][lane]
    }
    const float bb1 = b1[lane], bb2 = b2[lane];
    __syncthreads();

    const int gw = blockIdx.x * 4 + wave, nw = gridDim.x * 4;
    for (int e = gw; e < E; e += nw) {
        const int eu = __builtin_amdgcn_readfirstlane(e);
        const int s = src[eu], d = dst[eu];
        const float x = h_edge[eu * 64 + lane];
        const float a = AB[s * 128 + lane];
        const float b = AB[d * 128 + 64 + lane];

        sx[wave][lane] = x;
        WB();
        float t = bb1 + a + b;
#pragma unroll
        for (int k4 = 0; k4 < 16; ++k4) {
            float4 xv = *(const float4*)&sx[wave][k4 * 4];
            t = fmaf(xv.x, w1c[4 * k4 + 0], t);
            t = fmaf(xv.y, w1c[4 * k4 + 1], t);
            t = fmaf(xv.z, w1c[4 * k4 + 2], t);
            t = fmaf(xv.w, w1c[4 * k4 + 3], t);
        }
        t = fmaxf(t, 0.f);

        st[wave][lane] = t;
        WB();
        float m = bb2;
#pragma unroll
        for (int k4 = 0; k4 < 16; ++k4) {
            float4 tv = *(const float4*)&st[wave][k4 * 4];
            m = fmaf(tv.x, w2[4 * k4 + 0], m);
            m = fmaf(tv.y, w2[4 * k4 + 1], m);
            m = fmaf(tv.z, w2[4 * k4 + 2], m);
            m = fmaf(tv.w, w2[4 * k4 + 3], m);
        }
        m = fmaxf(m, 0.f);
        WB();   // all lanes done reading sx/st before next iteration overwrites

        const int g = node_graph_id[d];
        atomicAdd(&sgg[g * 64 + lane], m);
    }
    __syncthreads();

    for (int i = threadIdx.x; i < 128 * 64; i += 256) {
        float v = sgg[i];
        if (v != 0.f) atomicAdd(&gg[i], v);
    }
}

// ---------------------------------------------------------------------------
// K2: per-graph epilogue. block = 128 threads, one block per graph.
__global__ __launch_bounds__(128) void k_final(
    const float* __restrict__ u, const float* __restrict__ gg,
    const int* __restrict__ cnt,
    const float* __restrict__ Wn, const float* __restrict__ bn,
    const float* __restrict__ Wg, const float* __restrict__ bg,
    float* __restrict__ out)
{
    const int g = blockIdx.x, t = threadIdx.x;
    __shared__ float sgg[64];
    __shared__ float sn[64];
    if (t < 64) sgg[t] = gg[g * 64 + t];
    __syncthreads();
    if (t < 64) {
        float acc = bn[t] * (float)cnt[g];
        for (int k = 0; k < 64; ++k)
            acc = fmaf(sgg[k], Wn[k * 64 + t], acc);
        sn[t] = acc;
    }
    __syncthreads();
    float acc = bg[t];
    for (int k = 0; k < 128; ++k)
        acc = fmaf(u[g * 128 + k], Wg[k * 128 + t], acc);
    for (int k = 0; k < 64; ++k)
        acc = fmaf(sn[k], Wg[(128 + k) * 128 + t], acc);
    out[g * 128 + t] = fmaxf(acc, 0.f);
}

// ---------------------------------------------------------------------------
extern "C" void kernel_launch(void* const* d_in, const int* in_sizes, int n_in,
                              void* d_out, int out_size, void* d_ws, size_t ws_size,
                              hipStream_t stream)
{
    const float* h_node = (const float*)d_in[0];
    const float* h_edge = (const float*)d_in[1];
    const float* u      = (const float*)d_in[2];
    const float* W1     = (const float*)d_in[3];
    const float* b1     = (const float*)d_in[4];
    const float* W2     = (const float*)d_in[5];
    const float* b2     = (const float*)d_in[6];
    const float* Wn     = (const float*)d_in[7];
    const float* bn     = (const float*)d_in[8];
    const float* Wg     = (const float*)d_in[9];
    const float* bg     = (const float*)d_in[10];
    const int*   src    = (const int*)d_in[11];
    const int*   dst    = (const int*)d_in[12];
    const int*   ngid   = (const int*)d_in[13];

    const int N = in_sizes[0] / 64;
    const int E = in_sizes[1] / 64;
    const int G = in_sizes[2] / 128;   // 128

    // workspace layout
    float* AB  = (float*)d_ws;                         // N*128 floats (26.2 MB)
    float* gg  = AB + (size_t)N * 128;                 // G*64 floats
    int*   cnt = (int*)(gg + (size_t)G * 64);          // G ints

    hipMemsetAsync(gg, 0, (size_t)G * 64 * sizeof(float) + G * sizeof(int), stream);

    k_node_ab<<<512, 256, 0, stream>>>(h_node, W1, AB, N);
    k_count<<<(N + 255) / 256, 256, 0, stream>>>(ngid, cnt, N);
    k_edge<<<768, 256, 0, stream>>>(h_edge, AB, W1, b1, W2, b2, src, dst, ngid, gg, E);
    k_final<<<G, 128, 0, stream>>>(u, gg, cnt, Wn, bn, Wg, bg, (float*)d_out);
}

// Round 2
// 534.726 us; speedup vs baseline: 1.6832x; 1.6832x over previous
//
#include <hip/hip_runtime.h>

// Problem constants (fixed by the reference):
//   N=51200 nodes, E=800000 edges (E%16==0), G=128 graphs, DIN=DE=DOUT=64, DG=128
// Math restructuring:
//   AB[i][0:64]   = h_node[i] @ W1[0:64,:]      (A)
//   AB[i][64:128] = h_node[i] @ W1[64:128,:]    (B)
//   msg_e  = relu(relu(A[src]+B[dst]+h_edge@W1c+b1) @ W2 + b2)
//   gg[g]  = sum_{e: graph(dst_e)=g} msg_e                   [G,64]
//   out[g] = relu(concat(u[g], gg[g]@Wn + cnt_g*bn) @ Wg + bg)
// MFMA mapping (16x16x32 bf16): feats = rows (M), edges/nodes = cols (N),
//   C/D layout: col=lane&15, row=quad*4+reg; A/B frag: [free=lane&15][k=quad*8+j]

typedef __attribute__((ext_vector_type(8))) short short8;
typedef __attribute__((ext_vector_type(4))) float f32x4;

#define WB() __builtin_amdgcn_wave_barrier()

__device__ inline unsigned short f2bfu(float x) {
    unsigned u = __builtin_bit_cast(unsigned, x);
    u += 0x7fffu + ((u >> 16) & 1u);          // round-to-nearest-even
    return (unsigned short)(u >> 16);
}
__device__ inline short f2bf(float x) { return (short)f2bfu(x); }
__device__ inline unsigned pack2(float a, float b) {
    return (unsigned)f2bfu(a) | ((unsigned)f2bfu(b) << 16);
}
__device__ inline short8 cvt8(f32x4 a, f32x4 b) {
    short8 r;
    r[0]=f2bf(a[0]); r[1]=f2bf(a[1]); r[2]=f2bf(a[2]); r[3]=f2bf(a[3]);
    r[4]=f2bf(b[0]); r[5]=f2bf(b[1]); r[6]=f2bf(b[2]); r[7]=f2bf(b[3]);
    return r;
}

// ---------------------------------------------------------------------------
// K0: AB via MFMA. 16 nodes per wave-iteration.
// D[feat(128)][node(16)] = sum_k W1ab^T[feat][k] * h_node[node][k]
__global__ __launch_bounds__(256) void k_node_mfma(
    const float* __restrict__ h_node, const float* __restrict__ W1,
    float* __restrict__ AB, int N)
{
    const int lane = threadIdx.x & 63;
    const int quad = lane >> 4, col = lane & 15;

    // weight fragments: feat = mt*16+col (0..127), k = ks*32+quad*8+j
    short8 wf[2][8];
    for (int ks = 0; ks < 2; ++ks)
        for (int mt = 0; mt < 8; ++mt) {
            const int feat = mt * 16 + col;
            const float* Wc = W1 + (size_t)((feat >> 6) * 64) * 64 + (feat & 63);
            short8 f;
            for (int j = 0; j < 8; ++j) {
                const int k = ks * 32 + quad * 8 + j;
                f[j] = f2bf(Wc[(size_t)k * 64]);
            }
            wf[ks][mt] = f;
        }

    const int wid = (blockIdx.x * blockDim.x + threadIdx.x) >> 6;
    const int nw  = (gridDim.x * blockDim.x) >> 6;
    const int ntiles = N >> 4;
    for (int t = wid; t < ntiles; t += nw) {
        const int node = t * 16 + col;
        const float* xr = h_node + (size_t)node * 64 + quad * 8;
        f32x4 x0 = *(const f32x4*)(xr);
        f32x4 x1 = *(const f32x4*)(xr + 4);
        f32x4 x2 = *(const f32x4*)(xr + 32);
        f32x4 x3 = *(const f32x4*)(xr + 36);
        short8 xb0 = cvt8(x0, x1), xb1 = cvt8(x2, x3);

        f32x4 acc[8];
#pragma unroll
        for (int mt = 0; mt < 8; ++mt) acc[mt] = (f32x4){0.f, 0.f, 0.f, 0.f};
#pragma unroll
        for (int mt = 0; mt < 8; ++mt)
            acc[mt] = __builtin_amdgcn_mfma_f32_16x16x32_bf16(wf[0][mt], xb0, acc[mt], 0, 0, 0);
#pragma unroll
        for (int mt = 0; mt < 8; ++mt)
            acc[mt] = __builtin_amdgcn_mfma_f32_16x16x32_bf16(wf[1][mt], xb1, acc[mt], 0, 0, 0);

        float* orow = AB + (size_t)node * 128 + quad * 4;
#pragma unroll
        for (int mt = 0; mt < 8; ++mt)
            *(f32x4*)(orow + mt * 16) = acc[mt];
    }
}

// ---------------------------------------------------------------------------
// K1: fused edge MLP (MFMA) + per-graph scatter. 16 edges per wave-iteration.
__global__ __launch_bounds__(256) void k_edge_mfma(
    const float* __restrict__ h_edge, const float* __restrict__ AB,
    const float* __restrict__ W1, const float* __restrict__ b1,
    const float* __restrict__ W2, const float* __restrict__ b2,
    const int* __restrict__ src, const int* __restrict__ dst,
    const int* __restrict__ ngid,
    float* __restrict__ gg, int E)
{
    __shared__ float sgg[128 * 65];        // padded per-graph accumulator (33.3 KB)
    __shared__ short tlds[4][16 * 72];     // per-wave t tile, stride 72 bf16 (9.2 KB)
    const int wave = threadIdx.x >> 6, lane = threadIdx.x & 63;
    const int quad = lane >> 4, col = lane & 15;

    for (int i = threadIdx.x; i < 128 * 65; i += 256) sgg[i] = 0.f;

    // weight fragments (loaded once): feat = mt*16+col, k = ks*32+quad*8+j
    short8 w1f[2][4], w2f[2][4];
    for (int ks = 0; ks < 2; ++ks)
        for (int mt = 0; mt < 4; ++mt) {
            const int feat = mt * 16 + col;
            short8 f1, f2;
            for (int j = 0; j < 8; ++j) {
                const int k = ks * 32 + quad * 8 + j;
                f1[j] = f2bf(W1[(size_t)(128 + k) * 64 + feat]);
                f2[j] = f2bf(W2[(size_t)k * 64 + feat]);
            }
            w1f[ks][mt] = f1; w2f[ks][mt] = f2;
        }
    f32x4 bb1[4], bb2[4];
#pragma unroll
    for (int mt = 0; mt < 4; ++mt) {
        bb1[mt] = *(const f32x4*)(b1 + mt * 16 + quad * 4);
        bb2[mt] = *(const f32x4*)(b2 + mt * 16 + quad * 4);
    }
    __syncthreads();

    short* tl = tlds[wave];
    const int wid = (blockIdx.x * blockDim.x + threadIdx.x) >> 6;
    const int nw  = (gridDim.x * blockDim.x) >> 6;
    const int ntiles = E >> 4;             // E % 16 == 0
    for (int t = wid; t < ntiles; t += nw) {
        const int e = t * 16 + col;
        const int s = src[e], d = dst[e];
        const int g = ngid[d];

        // gather A[src], B[dst] rows (float4 per feat-tile) + h_edge fragments
        const float* ar = AB + (size_t)s * 128 + quad * 4;
        const float* br = AB + (size_t)d * 128 + 64 + quad * 4;
        f32x4 av[4], bv[4];
#pragma unroll
        for (int mt = 0; mt < 4; ++mt) {
            av[mt] = *(const f32x4*)(ar + mt * 16);
            bv[mt] = *(const f32x4*)(br + mt * 16);
        }
        const float* xr = h_edge + (size_t)e * 64 + quad * 8;
        f32x4 x0 = *(const f32x4*)(xr);
        f32x4 x1 = *(const f32x4*)(xr + 4);
        f32x4 x2 = *(const f32x4*)(xr + 32);
        f32x4 x3 = *(const f32x4*)(xr + 36);
        short8 xb0 = cvt8(x0, x1), xb1 = cvt8(x2, x3);

        // layer 1: acc = b1 + A[src] + B[dst] + h_edge @ W1c
        f32x4 acc[4];
#pragma unroll
        for (int mt = 0; mt < 4; ++mt) acc[mt] = bb1[mt] + av[mt] + bv[mt];
#pragma unroll
        for (int mt = 0; mt < 4; ++mt)
            acc[mt] = __builtin_amdgcn_mfma_f32_16x16x32_bf16(w1f[0][mt], xb0, acc[mt], 0, 0, 0);
#pragma unroll
        for (int mt = 0; mt < 4; ++mt)
            acc[mt] = __builtin_amdgcn_mfma_f32_16x16x32_bf16(w1f[1][mt], xb1, acc[mt], 0, 0, 0);

        // relu -> bf16 -> LDS tile [edge][feat] (stride 72)
#pragma unroll
        for (int mt = 0; mt < 4; ++mt) {
            uint2 p;
            p.x = pack2(fmaxf(acc[mt][0], 0.f), fmaxf(acc[mt][1], 0.f));
            p.y = pack2(fmaxf(acc[mt][2], 0.f), fmaxf(acc[mt][3], 0.f));
            *(uint2*)&tl[col * 72 + mt * 16 + quad * 4] = p;
        }
        WB();
        short8 tb0 = *(const short8*)&tl[col * 72 + quad * 8];
        short8 tb1 = *(const short8*)&tl[col * 72 + 32 + quad * 8];

        // layer 2
        f32x4 acc2[4];
#pragma unroll
        for (int mt = 0; mt < 4; ++mt) acc2[mt] = bb2[mt];
#pragma unroll
        for (int mt = 0; mt < 4; ++mt)
            acc2[mt] = __builtin_amdgcn_mfma_f32_16x16x32_bf16(w2f[0][mt], tb0, acc2[mt], 0, 0, 0);
#pragma unroll
        for (int mt = 0; mt < 4; ++mt)
            acc2[mt] = __builtin_amdgcn_mfma_f32_16x16x32_bf16(w2f[1][mt], tb1, acc2[mt], 0, 0, 0);
        WB();   // reads of tl complete before next iteration overwrites

        // relu + per-graph scatter into padded LDS table
        float* sg = sgg + g * 65;
#pragma unroll
        for (int mt = 0; mt < 4; ++mt) {
#pragma unroll
            for (int r = 0; r < 4; ++r)
                atomicAdd(&sg[mt * 16 + quad * 4 + r], fmaxf(acc2[mt][r], 0.f));
        }
    }
    __syncthreads();

    for (int i = threadIdx.x; i < 128 * 64; i += 256) {
        const float v = sgg[(i >> 6) * 65 + (i & 63)];
        if (v != 0.f) atomicAdd(&gg[i], v);
    }
}

// ---------------------------------------------------------------------------
// K2: per-graph epilogue. One block of 128 threads per graph.
// cnt_g via binary search on sorted node_graph_id (no separate count kernel).
__global__ __launch_bounds__(128) void k_final(
    const float* __restrict__ u, const float* __restrict__ gg,
    const int* __restrict__ ngid, int N,
    const float* __restrict__ Wn, const float* __restrict__ bn,
    const float* __restrict__ Wg, const float* __restrict__ bg,
    float* __restrict__ out)
{
    const int g = blockIdx.x, t = threadIdx.x;
    __shared__ float sgg[64];
    __shared__ float sn[64];
    __shared__ int scnt;
    if (t == 0) {
        int lo = 0, hi = N;
        while (lo < hi) { int m = (lo + hi) >> 1; if (ngid[m] < g) lo = m + 1; else hi = m; }
        const int a = lo;
        lo = 0; hi = N;
        while (lo < hi) { int m = (lo + hi) >> 1; if (ngid[m] < g + 1) lo = m + 1; else hi = m; }
        scnt = lo - a;
    }
    if (t < 64) sgg[t] = gg[g * 64 + t];
    __syncthreads();
    if (t < 64) {
        float acc = bn[t] * (float)scnt;
        for (int k = 0; k < 64; ++k)
            acc = fmaf(sgg[k], Wn[k * 64 + t], acc);
        sn[t] = acc;
    }
    __syncthreads();
    float acc = bg[t];
    for (int k = 0; k < 128; ++k)
        acc = fmaf(u[g * 128 + k], Wg[k * 128 + t], acc);
    for (int k = 0; k < 64; ++k)
        acc = fmaf(sn[k], Wg[(128 + k) * 128 + t], acc);
    out[g * 128 + t] = fmaxf(acc, 0.f);
}

// ---------------------------------------------------------------------------
extern "C" void kernel_launch(void* const* d_in, const int* in_sizes, int n_in,
                              void* d_out, int out_size, void* d_ws, size_t ws_size,
                              hipStream_t stream)
{
    const float* h_node = (const float*)d_in[0];
    const float* h_edge = (const float*)d_in[1];
    const float* u      = (const float*)d_in[2];
    const float* W1     = (const float*)d_in[3];
    const float* b1     = (const float*)d_in[4];
    const float* W2     = (const float*)d_in[5];
    const float* b2     = (const float*)d_in[6];
    const float* Wn     = (const float*)d_in[7];
    const float* bn     = (const float*)d_in[8];
    const float* Wg     = (const float*)d_in[9];
    const float* bg     = (const float*)d_in[10];
    const int*   src    = (const int*)d_in[11];
    const int*   dst    = (const int*)d_in[12];
    const int*   ngid   = (const int*)d_in[13];

    const int N = in_sizes[0] / 64;
    const int E = in_sizes[1] / 64;
    const int G = in_sizes[2] / 128;

    float* AB = (float*)d_ws;                      // N*128 floats
    float* gg = AB + (size_t)N * 128;              // G*64 floats

    hipMemsetAsync(gg, 0, (size_t)G * 64 * sizeof(float), stream);

    k_node_mfma<<<400, 256, 0, stream>>>(h_node, W1, AB, N);
    k_edge_mfma<<<768, 256, 0, stream>>>(h_edge, AB, W1, b1, W2, b2, src, dst, ngid, gg, E);
    k_final<<<G, 128, 0, stream>>>(u, gg, ngid, N, Wn, bn, Wg, bg, (float*)d_out);
}